// Round 18
// baseline (532.375 us; speedup 1.0000x reference)
//
#include <hip/hip_runtime.h>
#include <math.h>

#define Bn 8
#define Cn 64
#define Hn 96
#define Wn 96
#define HWn (Hn*Wn)
#define OCn 64
#define Kn 9
#define OFFCn 27
#define NPIX (Bn*HWn)        // 73728 = 1152*64
#define PGRPS (NPIX/64)      // 1152 pixel groups
#define BLK_PER_B (HWn/64)   // 144 blocks per batch image = PGRPS/8

// ws layout (dwords): wpk1[15552] | wpk2m[131072 shorts]
#define WPK1_N 15552
#define WPK2M_SHORTS 131072
#define WS_DWORDS (WPK1_N + WPK2M_SHORTS/2)
#define WS_BYTES  ((size_t)WS_DWORDS*4)   // ~320 KB

typedef __attribute__((ext_vector_type(8))) short short8v;
typedef __attribute__((ext_vector_type(4))) float f32x4;

static __device__ __forceinline__ unsigned short bf16_rne(float f) {
    unsigned int u = __float_as_uint(f);
    return (unsigned short)((u + 0x7FFFu + ((u >> 16) & 1u)) >> 16);
}
static __device__ __forceinline__ float bf16_back(unsigned short h) {
    return __uint_as_float(((unsigned int)h) << 16);
}

// ============ wprep: wpk1 stream (offset conv) + wpk2m MFMA A-frags ===========
__global__ __launch_bounds__(256) void dcn_wprep(
    const float* __restrict__ w_off,
    const float* __restrict__ weight,
    float* __restrict__ wpk1,
    short* __restrict__ wpk2m)
{
    const int g = blockIdx.x * 256 + threadIdx.x;   // 64 blocks -> 16384
    if (g < WPK1_N) {
        const int c_all = g / 243;
        const int och   = (g % 243) / 9;
        const int ki    = g % 9;
        wpk1[g] = w_off[(och * 64 + c_all) * 9 + ki];
    }
    if (g < WPK2M_SHORTS / 8) {
        const int lane = g & 63;
        const int oct  = (g >> 6) & 3;
        const int c    = g >> 8;
        const int oc   = oct * 16 + (lane & 15);
        const float* wsrc = weight + (oc * 64 + c) * 9;
        short8v v;
#pragma unroll
        for (int j = 0; j < 8; ++j) {
            const int s = ((lane >> 4) & 3) * 8 + j;
            float f = 0.0f;
            if (s <= 8)                  f = wsrc[s];
            else if (s >= 16 && s <= 24) f = wsrc[s - 16];
            v[j] = (short)bf16_rne(f);
        }
        ((short8v*)wpk2m)[g] = v;
    }
}

// ====== fused: offset conv -> params (regs) -> gather -> MFMA (R14 body) ======
// R18 change vs R14: request the 5-waves/SIMD register bin directly
// (VGPR budget 512/5 = 102) via amdgpu_waves_per_eu. R14's steady-state live
// set is ~90-100 VGPR; the 128 allocation was cap-filling. At VGPR<=102:
// 20 waves/CU and LDS 5x32KB = 160KB saturate together (+25% residency).
// launch_bounds arg2 is NOT used for this: measured cap law arg2=4 -> 64
// (R2/R16/R17 spill disasters).
__global__ __launch_bounds__(256) __attribute__((amdgpu_waves_per_eu(5)))
void dcn_fused(
    const float* __restrict__ x,
    const float* __restrict__ wpk1,
    const float* __restrict__ b_off,
    const short* __restrict__ wpk2m,
    const float* __restrict__ bias,
    float* __restrict__ out)
{
    __shared__ short smp[32 * 64 * 8];      // 32 KB; phase 1 aliases as float
    float* lds1 = (float*)smp;              // needs 4*64*27*4 = 27.6 KB <= 32 KB

    const int tid  = threadIdx.x;
    const int lane = tid & 63;
    const int wv   = tid >> 6;
    const int cbase = __builtin_amdgcn_readfirstlane(wv * 16);

    // XCD swizzle (1152 = 8 * 144, one image per XCD) -- R14-proven (FETCH 8x)
    const int bid = (blockIdx.x & 7) * BLK_PER_B + (blockIdx.x >> 3);

    const int p0  = bid * 64;
    const int b   = p0 / HWn;
    const int hwb = p0 % HWn;
    const int p   = p0 + lane;
    const int hw  = p % HWn;
    const int ho  = hw / Wn;
    const int wo  = hw % Wn;

    const float* xb = x + b * (Cn * HWn);

    // ---------------- Phase 1: offset conv (c-split across waves) -------------
    float om[OFFCn];
    {
        int   toff[Kn];
        float tval[Kn];
#pragma unroll
        for (int ki = 0; ki < Kn; ++ki) {
            const int yy = ho + ki / 3 - 1, xx = wo + ki % 3 - 1;
            const bool v = (yy >= 0) && (yy < Hn) && (xx >= 0) && (xx < Wn);
            toff[ki] = min(max(yy, 0), Hn - 1) * Wn + min(max(xx, 0), Wn - 1);
            tval[ki] = v ? 1.0f : 0.0f;
        }

#pragma unroll
        for (int j = 0; j < OFFCn; ++j) om[j] = 0.0f;

        const float* wstream = wpk1 + cbase * 243;   // wave-uniform, contiguous
        for (int ci = 0; ci < 16; ++ci) {
            const float* xc = xb + (cbase + ci) * HWn;
            float xk[Kn];
#pragma unroll
            for (int ki = 0; ki < Kn; ++ki)
                xk[ki] = xc[toff[ki]] * tval[ki];

            const float* wc = wstream + ci * 243;
#pragma unroll
            for (int och = 0; och < OFFCn; ++och) {
                const float* wp = wc + och * 9;
                float a = om[och];
#pragma unroll
                for (int ki = 0; ki < Kn; ++ki)
                    a = fmaf(xk[ki], wp[ki], a);
                om[och] = a;
            }
        }

        // LDS reduce (stride 27 dwords, gcd(27,32)=1 -> conflict-free)
#pragma unroll
        for (int j = 0; j < OFFCn; ++j)
            lds1[(wv * 64 + lane) * OFFCn + j] = om[j];
        __syncthreads();
#pragma unroll
        for (int j = 0; j < OFFCn; ++j) {
            float a = b_off[j];
#pragma unroll
            for (int ww = 0; ww < 4; ++ww)
                a += lds1[(ww * 64 + lane) * OFFCn + j];
            om[j] = a;
        }
    }

    // ---------------- Phase 1.5: sampling params (all waves, full set) --------
    float pw0[Kn], pw1[Kn], pw2[Kn], pw3[Kn];
    int   pav[Kn];
#pragma unroll
    for (int ki = 0; ki < Kn; ++ki) {
        const float py = om[ki]      + (float)(ki / 3 + ho - 1);
        const float px = om[Kn + ki] + (float)(ki % 3 + wo - 1);
        const float m  = 1.0f / (1.0f + __expf(-om[2 * Kn + ki]));

        const float y0f = floorf(py), x0f = floorf(px);
        const float ly = py - y0f, lx = px - x0f;
        const int iy0 = (int)y0f, ix0 = (int)x0f;
        const int iy1 = iy0 + 1,  ix1 = ix0 + 1;

        const float vy0 = (iy0 >= 0 && iy0 < Hn) ? 1.0f : 0.0f;
        const float vy1 = (iy1 >= 0 && iy1 < Hn) ? 1.0f : 0.0f;
        const float vx0 = (ix0 >= 0 && ix0 < Wn) ? 1.0f : 0.0f;
        const float vx1 = (ix1 >= 0 && ix1 < Wn) ? 1.0f : 0.0f;

        const int iy0c = min(max(iy0, 0), Hn - 1);
        const int iy1c = min(max(iy1, 0), Hn - 1);
        const int ix0c = min(max(ix0, 0), Wn - 1);
        const int ix1c = min(max(ix1, 0), Wn - 1);

        pw0[ki] = m * (1.0f - ly) * (1.0f - lx) * vy0 * vx0;
        pw1[ki] = m * (1.0f - ly) * lx          * vy0 * vx1;
        pw2[ki] = m * ly          * (1.0f - lx) * vy1 * vx0;
        pw3[ki] = m * ly          * lx          * vy1 * vx1;
        const int pa  = iy0c * Wn + ix0c;        // fits 16 bits
        const int dx  = ix1c - ix0c;             // 0/1
        const int dyw = (iy1c - iy0c) * Wn;      // 0/96
        pav[ki] = pa | (dx << 16) | (dyw << 17);
    }
    __syncthreads();   // lds1 reads done before smp is overwritten

    // ---------------- Phase 2: gather -> bf16 LDS -> MFMA ---------------------
    f32x4 acc[4];
#pragma unroll
    for (int oct = 0; oct < 4; ++oct) acc[oct] = (f32x4){0.f, 0.f, 0.f, 0.f};

    const short8v* afrags = (const short8v*)wpk2m;

    for (int chunk = 0; chunk < 8; ++chunk) {
        // gather: wave wv samples channels chunk*8 + wv*2 + {0,1}
#pragma unroll
        for (int cc = 0; cc < 2; ++cc) {
            const int cl = (wv << 1) | cc;               // 0..7 within chunk
            const float* xc = xb + (chunk * 8 + cl) * HWn;
            unsigned short hi[Kn], lo[Kn];
#pragma unroll
            for (int ki = 0; ki < Kn; ++ki) {
                const int av  = pav[ki];
                const int pa  = av & 0xFFFF;
                const int dx  = (av >> 16) & 1;
                const int dyw = av >> 17;
                const float* bp = xc + pa;
                const float v = pw0[ki] * bp[0] + pw1[ki] * bp[dx]
                              + pw2[ki] * bp[dyw] + pw3[ki] * bp[dyw + dx];
                hi[ki] = bf16_rne(v);
                lo[ki] = bf16_rne(v - bf16_back(hi[ki]));
            }
            short8v h0, h1, l0, l1;
#pragma unroll
            for (int j = 0; j < 8; ++j) { h0[j] = (short)hi[j]; l0[j] = (short)lo[j]; }
            h1 = (short8v){(short)hi[8], 0, 0, 0, 0, 0, 0, 0};
            l1 = (short8v){(short)lo[8], 0, 0, 0, 0, 0, 0, 0};
            const int r0 = cl * 4;
            *(short8v*)&smp[((r0 + 0) * 64 + lane) * 8] = h0;   // slots 0-7  (hi)
            *(short8v*)&smp[((r0 + 1) * 64 + lane) * 8] = h1;   // slots 8-15
            *(short8v*)&smp[((r0 + 2) * 64 + lane) * 8] = l0;   // slots 16-23 (lo)
            *(short8v*)&smp[((r0 + 3) * 64 + lane) * 8] = l1;   // slots 24-31
        }
        __syncthreads();

        // MFMA: ks == channel-in-chunk; B reused across 4 oc-tiles
#pragma unroll
        for (int ks = 0; ks < 8; ++ks) {
            const short8v bfrag = *(const short8v*)
                &smp[((ks * 4 + (lane >> 4)) * 64 + wv * 16 + (lane & 15)) * 8];
#pragma unroll
            for (int oct = 0; oct < 4; ++oct) {
                const short8v afrag =
                    afrags[(((chunk * 8 + ks) * 4) + oct) * 64 + lane];
                acc[oct] = __builtin_amdgcn_mfma_f32_16x16x32_bf16(
                    afrag, bfrag, acc[oct], 0, 0, 0);
            }
        }
        __syncthreads();
    }

    // ---------------- epilogue: C col=lane&15 -> px, row=(lane>>4)*4+r -> oc --
    const int pxl = wv * 16 + (lane & 15);
    float* ob = out + b * (OCn * HWn) + hwb + pxl;
#pragma unroll
    for (int oct = 0; oct < 4; ++oct) {
#pragma unroll
        for (int r = 0; r < 4; ++r) {
            const int oc = oct * 16 + ((lane >> 4) & 3) * 4 + r;
            ob[oc * HWn] = acc[oct][r] + bias[oc];
        }
    }
}

// ============================ fallback (R1 single-kernel, if ws too small) ====
__global__ __launch_bounds__(64) void dcn_r1(
    const float* __restrict__ x,
    const float* __restrict__ w_off,
    const float* __restrict__ b_off,
    const float* __restrict__ weight,
    const float* __restrict__ bias,
    float* __restrict__ out)
{
    const int p  = blockIdx.x * 64 + threadIdx.x;
    const int b  = p / HWn;
    const int hw = p % HWn;
    const int ho = hw / Wn;
    const int wo = hw % Wn;
    const float* xb = x + b * (Cn * HWn);

    float om[OFFCn];
#pragma unroll
    for (int j = 0; j < OFFCn; ++j) om[j] = b_off[j];

    int   toff[Kn];
    float tval[Kn];
#pragma unroll
    for (int ki = 0; ki < Kn; ++ki) {
        const int yy = ho + ki / 3 - 1, xx = wo + ki % 3 - 1;
        const bool v = (yy >= 0) && (yy < Hn) && (xx >= 0) && (xx < Wn);
        toff[ki] = min(max(yy, 0), Hn - 1) * Wn + min(max(xx, 0), Wn - 1);
        tval[ki] = v ? 1.0f : 0.0f;
    }
    for (int c = 0; c < Cn; ++c) {
        const float* xc = xb + c * HWn;
        float xk[Kn];
#pragma unroll
        for (int ki = 0; ki < Kn; ++ki) xk[ki] = xc[toff[ki]] * tval[ki];
        const float* wc = w_off + c * Kn;
#pragma unroll
        for (int och = 0; och < OFFCn; ++och) {
            const float* wp = wc + och * (Cn * Kn);
            float a = om[och];
#pragma unroll
            for (int ki = 0; ki < Kn; ++ki) a = fmaf(xk[ki], wp[ki], a);
            om[och] = a;
        }
    }
    float pw0[Kn], pw1[Kn], pw2[Kn], pw3[Kn];
    int   pa[Kn], pdx[Kn], pdyw[Kn];
#pragma unroll
    for (int ki = 0; ki < Kn; ++ki) {
        const float py = om[ki]      + (float)(ki / 3 + ho - 1);
        const float px = om[Kn + ki] + (float)(ki % 3 + wo - 1);
        const float m  = 1.0f / (1.0f + __expf(-om[2 * Kn + ki]));
        const float y0f = floorf(py), x0f = floorf(px);
        const float ly = py - y0f, lx = px - x0f;
        const int iy0 = (int)y0f, ix0 = (int)x0f;
        const int iy1 = iy0 + 1,  ix1 = ix0 + 1;
        const float vy0 = (iy0 >= 0 && iy0 < Hn) ? 1.0f : 0.0f;
        const float vy1 = (iy1 >= 0 && iy1 < Hn) ? 1.0f : 0.0f;
        const float vx0 = (ix0 >= 0 && ix0 < Wn) ? 1.0f : 0.0f;
        const float vx1 = (ix1 >= 0 && ix1 < Wn) ? 1.0f : 0.0f;
        const int iy0c = min(max(iy0, 0), Hn - 1);
        const int iy1c = min(max(iy1, 0), Hn - 1);
        const int ix0c = min(max(ix0, 0), Wn - 1);
        const int ix1c = min(max(ix1, 0), Wn - 1);
        pw0[ki] = m * (1.0f - ly) * (1.0f - lx) * vy0 * vx0;
        pw1[ki] = m * (1.0f - ly) * lx          * vy0 * vx1;
        pw2[ki] = m * ly          * (1.0f - lx) * vy1 * vx0;
        pw3[ki] = m * ly          * lx          * vy1 * vx1;
        pa[ki]   = iy0c * Wn + ix0c;
        pdx[ki]  = ix1c - ix0c;
        pdyw[ki] = (iy1c - iy0c) * Wn;
    }
    float acc[OCn];
#pragma unroll
    for (int oc = 0; oc < OCn; ++oc) acc[oc] = bias[oc];
    for (int c = 0; c < Cn; ++c) {
        const float* xc = xb + c * HWn;
        float s[Kn];
#pragma unroll
        for (int ki = 0; ki < Kn; ++ki) {
            const float* bp = xc + pa[ki];
            s[ki] = pw0[ki] * bp[0] + pw1[ki] * bp[pdx[ki]]
                  + pw2[ki] * bp[pdyw[ki]] + pw3[ki] * bp[pdyw[ki] + pdx[ki]];
        }
        const float* wc = weight + c * Kn;
#pragma unroll
        for (int oc = 0; oc < OCn; ++oc) {
            const float* wp = wc + oc * (Cn * Kn);
            float a = acc[oc];
#pragma unroll
            for (int ki = 0; ki < Kn; ++ki) a = fmaf(s[ki], wp[ki], a);
            acc[oc] = a;
        }
    }
    float* ob = out + b * (OCn * HWn) + hw;
#pragma unroll
    for (int oc = 0; oc < OCn; ++oc) ob[oc * HWn] = acc[oc];
}

extern "C" void kernel_launch(void* const* d_in, const int* in_sizes, int n_in,
                              void* d_out, int out_size, void* d_ws, size_t ws_size,
                              hipStream_t stream) {
    const float* x      = (const float*)d_in[0];
    const float* w_off  = (const float*)d_in[1];
    const float* b_off  = (const float*)d_in[2];
    const float* weight = (const float*)d_in[3];
    const float* bias   = (const float*)d_in[4];
    float* out = (float*)d_out;

    if (ws_size >= WS_BYTES) {
        float* wpk1  = (float*)d_ws;
        short* wpk2m = (short*)(wpk1 + WPK1_N);
        hipLaunchKernelGGL(dcn_wprep, dim3(64), dim3(256), 0, stream,
                           w_off, weight, wpk1, wpk2m);
        hipLaunchKernelGGL(dcn_fused, dim3(PGRPS), dim3(256), 0, stream,
                           x, wpk1, b_off, wpk2m, bias, out);
    } else {
        hipLaunchKernelGGL(dcn_r1, dim3(NPIX / 64), dim3(64), 0, stream,
                           x, w_off, b_off, weight, bias, out);
    }
}

// Round 19
// 237.272 us; speedup vs baseline: 2.2437x; 2.2437x over previous
//
#include <hip/hip_runtime.h>
#include <math.h>

#define Bn 8
#define Cn 64
#define Hn 96
#define Wn 96
#define HWn (Hn*Wn)
#define OCn 64
#define Kn 9
#define OFFCn 27
#define NPIX (Bn*HWn)        // 73728 = 1152*64
#define PGRPS (NPIX/64)      // 1152 pixel groups
#define BLK_PER_B (HWn/64)   // 144 blocks per batch image

// ws layout (dwords): pwbuf[36*NPIX] | abuf[9*NPIX] | wpk1[15552] | wpk2m shorts
#define WPK1_N 15552
#define WPK2M_SHORTS 131072
#define WS_DWORDS (45*NPIX + WPK1_N + WPK2M_SHORTS/2)
#define WS_BYTES  ((size_t)WS_DWORDS*4)   // ~13.9 MB

typedef __attribute__((ext_vector_type(8))) short short8v;
typedef __attribute__((ext_vector_type(4))) float f32x4;

static __device__ __forceinline__ unsigned short bf16_rne(float f) {
    unsigned int u = __float_as_uint(f);
    return (unsigned short)((u + 0x7FFFu + ((u >> 16) & 1u)) >> 16);
}
static __device__ __forceinline__ float bf16_back(unsigned short h) {
    return __uint_as_float(((unsigned int)h) << 16);
}

// ============ wprep: wpk1 stream (offset conv) + wpk2m MFMA A-frags ===========
__global__ __launch_bounds__(256) void dcn_wprep(
    const float* __restrict__ w_off,
    const float* __restrict__ weight,
    float* __restrict__ wpk1,
    short* __restrict__ wpk2m)
{
    const int g = blockIdx.x * 256 + threadIdx.x;   // 64 blocks -> 16384
    if (g < WPK1_N) {
        const int c_all = g / 243;
        const int och   = (g % 243) / 9;
        const int ki    = g % 9;
        wpk1[g] = w_off[(och * 64 + c_all) * 9 + ki];
    }
    if (g < WPK2M_SHORTS / 8) {
        const int lane = g & 63;
        const int oct  = (g >> 6) & 3;
        const int c    = g >> 8;
        const int oc   = oct * 16 + (lane & 15);
        const float* wsrc = weight + (oc * 64 + c) * 9;
        short8v v;
#pragma unroll
        for (int j = 0; j < 8; ++j) {
            const int s = ((lane >> 4) & 3) * 8 + j;
            float f = 0.0f;
            if (s <= 8)                  f = wsrc[s];
            else if (s >= 16 && s <= 24) f = wsrc[s - 16];
            v[j] = (short)bf16_rne(f);
        }
        ((short8v*)wpk2m)[g] = v;
    }
}

// ============================ K1: offset conv + sampling params (swizzled) ====
__global__ __launch_bounds__(256, 2) void dcn_k1(
    const float* __restrict__ x,
    const float* __restrict__ wpk1,
    const float* __restrict__ b_off,
    float* __restrict__ pwbuf,
    int*   __restrict__ abuf)
{
    __shared__ float lds[4 * 64 * OFFCn];   // 27.6 KB

    const int tid  = threadIdx.x;
    const int lane = tid & 63;
    const int wv   = tid >> 6;
    const int cbase = __builtin_amdgcn_readfirstlane(wv * 16);

    // XCD swizzle (R14-proven: FETCH 8x reduction mechanism)
    const int bid = (blockIdx.x & 7) * BLK_PER_B + (blockIdx.x >> 3);

    const int p  = bid * 64 + lane;
    const int b  = p / HWn;
    const int hw = p % HWn;
    const int ho = hw / Wn;
    const int wo = hw % Wn;

    const float* xb = x + b * (Cn * HWn);

    int   toff[Kn];
    float tval[Kn];
#pragma unroll
    for (int ki = 0; ki < Kn; ++ki) {
        const int yy = ho + ki / 3 - 1, xx = wo + ki % 3 - 1;
        const bool v = (yy >= 0) && (yy < Hn) && (xx >= 0) && (xx < Wn);
        toff[ki] = min(max(yy, 0), Hn - 1) * Wn + min(max(xx, 0), Wn - 1);
        tval[ki] = v ? 1.0f : 0.0f;
    }

    float om[OFFCn];
#pragma unroll
    for (int j = 0; j < OFFCn; ++j) om[j] = 0.0f;

    const float* wstream = wpk1 + cbase * 243;   // wave-uniform, contiguous
    for (int ci = 0; ci < 16; ++ci) {
        const float* xc = xb + (cbase + ci) * HWn;
        float xk[Kn];
#pragma unroll
        for (int ki = 0; ki < Kn; ++ki)
            xk[ki] = xc[toff[ki]] * tval[ki];

        const float* wc = wstream + ci * 243;
#pragma unroll
        for (int och = 0; och < OFFCn; ++och) {
            const float* wp = wc + och * 9;
            float a = om[och];
#pragma unroll
            for (int ki = 0; ki < Kn; ++ki)
                a = fmaf(xk[ki], wp[ki], a);
            om[och] = a;
        }
    }

#pragma unroll
    for (int j = 0; j < OFFCn; ++j)
        lds[(wv * 64 + lane) * OFFCn + j] = om[j];
    __syncthreads();
#pragma unroll
    for (int j = 0; j < OFFCn; ++j) {
        float a = b_off[j];
#pragma unroll
        for (int ww = 0; ww < 4; ++ww)
            a += lds[(ww * 64 + lane) * OFFCn + j];
        om[j] = a;
    }

    float pw0[Kn], pw1[Kn], pw2[Kn], pw3[Kn];
    int   pav[Kn];
#pragma unroll
    for (int ki = 0; ki < Kn; ++ki) {
        const float py = om[ki]      + (float)(ki / 3 + ho - 1);
        const float px = om[Kn + ki] + (float)(ki % 3 + wo - 1);
        const float m  = 1.0f / (1.0f + __expf(-om[2 * Kn + ki]));

        const float y0f = floorf(py), x0f = floorf(px);
        const float ly = py - y0f, lx = px - x0f;
        const int iy0 = (int)y0f, ix0 = (int)x0f;
        const int iy1 = iy0 + 1,  ix1 = ix0 + 1;

        const float vy0 = (iy0 >= 0 && iy0 < Hn) ? 1.0f : 0.0f;
        const float vy1 = (iy1 >= 0 && iy1 < Hn) ? 1.0f : 0.0f;
        const float vx0 = (ix0 >= 0 && ix0 < Wn) ? 1.0f : 0.0f;
        const float vx1 = (ix1 >= 0 && ix1 < Wn) ? 1.0f : 0.0f;

        const int iy0c = min(max(iy0, 0), Hn - 1);
        const int iy1c = min(max(iy1, 0), Hn - 1);
        const int ix0c = min(max(ix0, 0), Wn - 1);
        const int ix1c = min(max(ix1, 0), Wn - 1);

        pw0[ki] = m * (1.0f - ly) * (1.0f - lx) * vy0 * vx0;
        pw1[ki] = m * (1.0f - ly) * lx          * vy0 * vx1;
        pw2[ki] = m * ly          * (1.0f - lx) * vy1 * vx0;
        pw3[ki] = m * ly          * lx          * vy1 * vx1;
        const int pa  = iy0c * Wn + ix0c;        // fits 16 bits
        const int dx  = ix1c - ix0c;             // 0/1
        const int dyw = (iy1c - iy0c) * Wn;      // 0/96
        pav[ki] = pa | (dx << 16) | (dyw << 17);
    }

    if (wv == 0) {
#pragma unroll
        for (int ki = 0; ki < Kn; ++ki) pwbuf[(0 * Kn + ki) * NPIX + p] = pw0[ki];
#pragma unroll
        for (int ki = 0; ki < Kn; ++ki) abuf[ki * NPIX + p] = pav[ki];
    } else if (wv == 1) {
#pragma unroll
        for (int ki = 0; ki < Kn; ++ki) pwbuf[(1 * Kn + ki) * NPIX + p] = pw1[ki];
    } else if (wv == 2) {
#pragma unroll
        for (int ki = 0; ki < Kn; ++ki) pwbuf[(2 * Kn + ki) * NPIX + p] = pw2[ki];
    } else {
#pragma unroll
        for (int ki = 0; ki < Kn; ++ki) pwbuf[(3 * Kn + ki) * NPIX + p] = pw3[ki];
    }
}

// ====== K2: gather -> bf16 LDS (b128-only) -> MFMA, swizzled ==================
// R12 body + XCD swizzle. Params loaded from ws (no om/toff live) -> lower
// peak register pressure than the fused form -> compiler headroom to batch
// the 36 independent gathers per channel.
__global__ __launch_bounds__(256, 2) void dcn_k2(
    const float* __restrict__ x,
    const short* __restrict__ wpk2m,
    const float* __restrict__ bias,
    const float* __restrict__ pwbuf,
    const int*   __restrict__ abuf,
    float* __restrict__ out)
{
    __shared__ short smp[32 * 64 * 8];   // 32 KB

    const int tid  = threadIdx.x;
    const int lane = tid & 63;
    const int wv   = tid >> 6;           // 0..3 = px-tile

    // XCD swizzle
    const int bid = (blockIdx.x & 7) * BLK_PER_B + (blockIdx.x >> 3);

    const int p0  = bid * 64;
    const int b   = p0 / HWn;
    const int hwb = p0 % HWn;
    const int p   = p0 + lane;

    const float* xb = x + b * (Cn * HWn);

    float pw0[Kn], pw1[Kn], pw2[Kn], pw3[Kn];
    int   pav[Kn];
#pragma unroll
    for (int ki = 0; ki < Kn; ++ki) pw0[ki] = pwbuf[(0 * Kn + ki) * NPIX + p];
#pragma unroll
    for (int ki = 0; ki < Kn; ++ki) pw1[ki] = pwbuf[(1 * Kn + ki) * NPIX + p];
#pragma unroll
    for (int ki = 0; ki < Kn; ++ki) pw2[ki] = pwbuf[(2 * Kn + ki) * NPIX + p];
#pragma unroll
    for (int ki = 0; ki < Kn; ++ki) pw3[ki] = pwbuf[(3 * Kn + ki) * NPIX + p];
#pragma unroll
    for (int ki = 0; ki < Kn; ++ki) pav[ki] = abuf[ki * NPIX + p];

    f32x4 acc[4];
#pragma unroll
    for (int oct = 0; oct < 4; ++oct) acc[oct] = (f32x4){0.f, 0.f, 0.f, 0.f};

    const short8v* afrags = (const short8v*)wpk2m;

    for (int chunk = 0; chunk < 8; ++chunk) {
        // ---- gather: wave wv samples channels chunk*8 + wv*2 + {0,1} ----
#pragma unroll
        for (int cc = 0; cc < 2; ++cc) {
            const int cl = (wv << 1) | cc;               // 0..7 within chunk
            const float* xc = xb + (chunk * 8 + cl) * HWn;
            unsigned short hi[Kn], lo[Kn];
#pragma unroll
            for (int ki = 0; ki < Kn; ++ki) {
                const int av  = pav[ki];
                const int pa  = av & 0xFFFF;
                const int dx  = (av >> 16) & 1;
                const int dyw = av >> 17;
                const float* bp = xc + pa;
                const float v = pw0[ki] * bp[0] + pw1[ki] * bp[dx]
                              + pw2[ki] * bp[dyw] + pw3[ki] * bp[dyw + dx];
                hi[ki] = bf16_rne(v);
                lo[ki] = bf16_rne(v - bf16_back(hi[ki]));
            }
            short8v h0, h1, l0, l1;
#pragma unroll
            for (int j = 0; j < 8; ++j) { h0[j] = (short)hi[j]; l0[j] = (short)lo[j]; }
            h1 = (short8v){(short)hi[8], 0, 0, 0, 0, 0, 0, 0};
            l1 = (short8v){(short)lo[8], 0, 0, 0, 0, 0, 0, 0};
            const int r0 = cl * 4;
            *(short8v*)&smp[((r0 + 0) * 64 + lane) * 8] = h0;   // slots 0-7  (hi)
            *(short8v*)&smp[((r0 + 1) * 64 + lane) * 8] = h1;   // slots 8-15
            *(short8v*)&smp[((r0 + 2) * 64 + lane) * 8] = l0;   // slots 16-23 (lo)
            *(short8v*)&smp[((r0 + 3) * 64 + lane) * 8] = l1;   // slots 24-31
        }
        __syncthreads();

        // ---- MFMA: ks == channel-in-chunk; B reused across 4 oc-tiles ----
#pragma unroll
        for (int ks = 0; ks < 8; ++ks) {
            const short8v bfrag = *(const short8v*)
                &smp[((ks * 4 + (lane >> 4)) * 64 + wv * 16 + (lane & 15)) * 8];
#pragma unroll
            for (int oct = 0; oct < 4; ++oct) {
                const short8v afrag =
                    afrags[(((chunk * 8 + ks) * 4) + oct) * 64 + lane];
                acc[oct] = __builtin_amdgcn_mfma_f32_16x16x32_bf16(
                    afrag, bfrag, acc[oct], 0, 0, 0);
            }
        }
        __syncthreads();
    }

    // ---- epilogue: C col=lane&15 -> px, row=(lane>>4)*4+r -> oc ----
    const int pxl = wv * 16 + (lane & 15);
    float* ob = out + b * (OCn * HWn) + hwb + pxl;
#pragma unroll
    for (int oct = 0; oct < 4; ++oct) {
#pragma unroll
        for (int r = 0; r < 4; ++r) {
            const int oc = oct * 16 + ((lane >> 4) & 3) * 4 + r;
            ob[oc * HWn] = acc[oct][r] + bias[oc];
        }
    }
}

// ============================ fallback (R1 single-kernel, if ws too small) ====
__global__ __launch_bounds__(64) void dcn_r1(
    const float* __restrict__ x,
    const float* __restrict__ w_off,
    const float* __restrict__ b_off,
    const float* __restrict__ weight,
    const float* __restrict__ bias,
    float* __restrict__ out)
{
    const int p  = blockIdx.x * 64 + threadIdx.x;
    const int b  = p / HWn;
    const int hw = p % HWn;
    const int ho = hw / Wn;
    const int wo = hw % Wn;
    const float* xb = x + b * (Cn * HWn);

    float om[OFFCn];
#pragma unroll
    for (int j = 0; j < OFFCn; ++j) om[j] = b_off[j];

    int   toff[Kn];
    float tval[Kn];
#pragma unroll
    for (int ki = 0; ki < Kn; ++ki) {
        const int yy = ho + ki / 3 - 1, xx = wo + ki % 3 - 1;
        const bool v = (yy >= 0) && (yy < Hn) && (xx >= 0) && (xx < Wn);
        toff[ki] = min(max(yy, 0), Hn - 1) * Wn + min(max(xx, 0), Wn - 1);
        tval[ki] = v ? 1.0f : 0.0f;
    }
    for (int c = 0; c < Cn; ++c) {
        const float* xc = xb + c * HWn;
        float xk[Kn];
#pragma unroll
        for (int ki = 0; ki < Kn; ++ki) xk[ki] = xc[toff[ki]] * tval[ki];
        const float* wc = w_off + c * Kn;
#pragma unroll
        for (int och = 0; och < OFFCn; ++och) {
            const float* wp = wc + och * (Cn * Kn);
            float a = om[och];
#pragma unroll
            for (int ki = 0; ki < Kn; ++ki) a = fmaf(xk[ki], wp[ki], a);
            om[och] = a;
        }
    }
    float pw0[Kn], pw1[Kn], pw2[Kn], pw3[Kn];
    int   pa[Kn], pdx[Kn], pdyw[Kn];
#pragma unroll
    for (int ki = 0; ki < Kn; ++ki) {
        const float py = om[ki]      + (float)(ki / 3 + ho - 1);
        const float px = om[Kn + ki] + (float)(ki % 3 + wo - 1);
        const float m  = 1.0f / (1.0f + __expf(-om[2 * Kn + ki]));
        const float y0f = floorf(py), x0f = floorf(px);
        const float ly = py - y0f, lx = px - x0f;
        const int iy0 = (int)y0f, ix0 = (int)x0f;
        const int iy1 = iy0 + 1,  ix1 = ix0 + 1;
        const float vy0 = (iy0 >= 0 && iy0 < Hn) ? 1.0f : 0.0f;
        const float vy1 = (iy1 >= 0 && iy1 < Hn) ? 1.0f : 0.0f;
        const float vx0 = (ix0 >= 0 && ix0 < Wn) ? 1.0f : 0.0f;
        const float vx1 = (ix1 >= 0 && ix1 < Wn) ? 1.0f : 0.0f;
        const int iy0c = min(max(iy0, 0), Hn - 1);
        const int iy1c = min(max(iy1, 0), Hn - 1);
        const int ix0c = min(max(ix0, 0), Wn - 1);
        const int ix1c = min(max(ix1, 0), Wn - 1);
        pw0[ki] = m * (1.0f - ly) * (1.0f - lx) * vy0 * vx0;
        pw1[ki] = m * (1.0f - ly) * lx          * vy0 * vx1;
        pw2[ki] = m * ly          * (1.0f - lx) * vy1 * vx0;
        pw3[ki] = m * ly          * lx          * vy1 * vx1;
        pa[ki]   = iy0c * Wn + ix0c;
        pdx[ki]  = ix1c - ix0c;
        pdyw[ki] = (iy1c - iy0c) * Wn;
    }
    float acc[OCn];
#pragma unroll
    for (int oc = 0; oc < OCn; ++oc) acc[oc] = bias[oc];
    for (int c = 0; c < Cn; ++c) {
        const float* xc = xb + c * HWn;
        float s[Kn];
#pragma unroll
        for (int ki = 0; ki < Kn; ++ki) {
            const float* bp = xc + pa[ki];
            s[ki] = pw0[ki] * bp[0] + pw1[ki] * bp[pdx[ki]]
                  + pw2[ki] * bp[pdyw[ki]] + pw3[ki] * bp[pdyw[ki] + pdx[ki]];
        }
        const float* wc = weight + c * Kn;
#pragma unroll
        for (int oc = 0; oc < OCn; ++oc) {
            const float* wp = wc + oc * (Cn * Kn);
            float a = acc[oc];
#pragma unroll
            for (int ki = 0; ki < Kn; ++ki) a = fmaf(s[ki], wp[ki], a);
            acc[oc] = a;
        }
    }
    float* ob = out + b * (OCn * HWn) + hw;
#pragma unroll
    for (int oc = 0; oc < OCn; ++oc) ob[oc * HWn] = acc[oc];
}

extern "C" void kernel_launch(void* const* d_in, const int* in_sizes, int n_in,
                              void* d_out, int out_size, void* d_ws, size_t ws_size,
                              hipStream_t stream) {
    const float* x      = (const float*)d_in[0];
    const float* w_off  = (const float*)d_in[1];
    const float* b_off  = (const float*)d_in[2];
    const float* weight = (const float*)d_in[3];
    const float* bias   = (const float*)d_in[4];
    float* out = (float*)d_out;

    if (ws_size >= WS_BYTES) {
        float* pwbuf = (float*)d_ws;
        int*   abuf  = (int*)((float*)d_ws + 36 * NPIX);
        float* wpk1  = (float*)d_ws + 45 * NPIX;
        short* wpk2m = (short*)(wpk1 + WPK1_N);
        hipLaunchKernelGGL(dcn_wprep, dim3(64), dim3(256), 0, stream,
                           w_off, weight, wpk1, wpk2m);
        hipLaunchKernelGGL(dcn_k1, dim3(PGRPS), dim3(256), 0, stream,
                           x, wpk1, b_off, pwbuf, abuf);
        hipLaunchKernelGGL(dcn_k2, dim3(PGRPS), dim3(256), 0, stream,
                           x, wpk2m, bias, pwbuf, abuf, out);
    } else {
        hipLaunchKernelGGL(dcn_r1, dim3(NPIX / 64), dim3(64), 0, stream,
                           x, w_off, b_off, weight, bias, out);
    }
}